// Round 17
// baseline (82.053 us; speedup 1.0000x reference)
//
#include <hip/hip_runtime.h>
#include <float.h>

#define B_ 16
#define D_ 64
#define L_ 8192
#define K_ 512
#define NBLOCKS 256
#define TILE_TOK 128
#define TILES_PER_BLOCK 4     // 1024 tiles / 256 blocks
#define EPS 0.0625f           // shifted-score gap err (fp16 dot) << EPS/2

// r17 = r16 tile body + r13 packaging. 256x4 (prologue amortized, single
// dispatch round); prologue writes half8 units (8 vectorized LDS writes,
// not 64 scalar 2B scatters -> conflicts die); block-wide float4 epilogue
// restored (WRITE back to ideal). 1 barrier/tile + prologue.

typedef __attribute__((ext_vector_type(8))) _Float16 half8;
typedef __attribute__((ext_vector_type(4))) float    f32x4;

__device__ __forceinline__ unsigned f32_sortable(float x) {
    unsigned u = __float_as_uint(x);
    return u ^ (((int)u >> 31) | 0x80000000u);   // ascending uint == ascending float
}

__global__ __launch_bounds__(512, 2)
void vq_mfma_kernel(const float* __restrict__ X, const float* __restrict__ E,
                    float* __restrict__ out_emb, float* __restrict__ out_idx)
{
    __shared__ __align__(16) short eF[32768];    // E fp16 A-frags, 64 KB
    __shared__ float esq_s[K_];                  // 2 KB
    __shared__ int   bestk_s[TILE_TOK];          // 512 B

    const int tid  = threadIdx.x;
    const int lane = tid & 63;
    const int wave = tid >> 6;        // 0..7
    const int lo4  = lane & 15;
    const int hi4  = lane >> 4;

    // ---- prologue (fused, vectorized): coalesced E reads -> esq (np
    //      sequential d-order, rounded squares) + half8 frag writes ----
    {
        int code = tid;                          // 0..511
        int blk = code >> 4, c15 = code & 15;
        float s = 0.f;
        #pragma unroll
        for (int dd = 0; dd < 8; ++dd) {
            half8 h8;
            #pragma unroll
            for (int j = 0; j < 8; ++j) {
                float v = E[(dd * 8 + j) * K_ + code];   // coalesced 2 KB/row
                float sq = v * v;
                asm volatile("" : "+v"(sq));     // np rounds the square first
                s = s + sq;                      // d ascending == np axis-0 order
                h8[j] = (_Float16)v;             // RNE
            }
            // unit (blk, kh=dd>>2), frag-lane fl=(dd&3)*16+c15  (r13-16 layout)
            ((half8*)eF)[(blk * 2 + (dd >> 2)) * 64 + (dd & 3) * 16 + c15] = h8;
        }
        esq_s[code] = s;
    }
    __syncthreads();

    for (int t = 0; t < TILES_PER_BLOCK; ++t) {
        int tile = blockIdx.x * TILES_PER_BLOCK + t;
        int b  = tile >> 6;                      // tile / 64
        int l0 = (tile & 63) << 7;               // (tile % 64) * 128
        const int token = wave * 16 + lo4;       // this lane's token (col)

        // ---- stage B-frags direct global->reg (frag layout) ----
        half8 bh0, bh1;
        {
            const float* xb = X + ((size_t)(b * 64 + hi4 * 8)) * L_ + l0 + token;
            #pragma unroll
            for (int j = 0; j < 8; ++j) {
                bh0[j] = (_Float16)xb[(size_t)j * L_];            // d = hi4*8+j
                bh1[j] = (_Float16)xb[(size_t)(32 + j) * L_];     // d = 32+hi4*8+j
            }
        }

        // ---- main: 32 code-blocks; shifted score (es - 2*dot); reg fold ----
        float m1 = FLT_MAX, m2 = FLT_MAX;
        int   k1 = 0x7FFFFFFF;
        #pragma unroll 8
        for (int blk = 0; blk < 32; ++blk) {
            half8 ah0 = ((const half8*)eF)[(blk * 2 + 0) * 64 + lane];
            half8 ah1 = ((const half8*)eF)[(blk * 2 + 1) * 64 + lane];
            f32x4 c = {0.f, 0.f, 0.f, 0.f};
            c = __builtin_amdgcn_mfma_f32_16x16x32_f16(ah0, bh0, c, 0, 0, 0);
            c = __builtin_amdgcn_mfma_f32_16x16x32_f16(ah1, bh1, c, 0, 0, 0);
            float4 es4 = *reinterpret_cast<const float4*>(&esq_s[blk * 16 + hi4 * 4]);
            float es[4] = {es4.x, es4.y, es4.z, es4.w};
            #pragma unroll
            for (int r = 0; r < 4; ++r) {
                float sc = fmaf(-2.0f, c[r], es[r]);   // xs const/token: gap invariant
                int   cd = blk * 16 + hi4 * 4 + r;     // ascending within lane
                if (sc < m1)      { m2 = m1; m1 = sc; k1 = cd; }
                else              { m2 = fminf(m2, sc); }
            }
        }

        // ---- merge 4 hi4-copies per token (xor 16, 32) — validated logic ---
        #pragma unroll
        for (int off = 16; off < 64; off <<= 1) {
            float ov = __shfl_xor(m1, off, 64);
            int   ok = __shfl_xor(k1, off, 64);
            float o2 = __shfl_xor(m2, off, 64);
            float n2 = fminf(fminf(m2, o2), fmaxf(m1, ov));
            if (ov < m1 || (ov == m1 && ok < k1)) { m1 = ov; k1 = ok; }
            m2 = n2;
        }

        // ---- flag near-ties; wave-local exact pass (np-bitexact) ----------
        unsigned long long bal = __ballot((lane < 16) && (m2 <= m1 + EPS));
        while (bal) {
            int tk = (int)__builtin_ctzll(bal);
            bal &= bal - 1;
            // xsq in-pass: np pairwise-8 (j = lane&7, groups redundant)
            float xs_e;
            {
                int j = lane & 7;
                float r = 0.f;
                #pragma unroll
                for (int m = 0; m < 8; ++m) {
                    float v = X[((size_t)(b * 64 + m * 8 + j)) * L_ + l0 + wave * 16 + tk];
                    float sq = v * v;
                    asm volatile("" : "+v"(sq)); // np rounds the square first
                    r = r + sq;                  // m ascending: np r8[j] order
                }
                r = r + __shfl_xor(r, 1, 64);    // (r0+r1) ...
                r = r + __shfl_xor(r, 2, 64);    // ((r0+r1)+(r2+r3)) ...
                r = r + __shfl_xor(r, 4, 64);    // full np pairwise tree
                xs_e = r;                        // identical in each 8-lane group
            }
            // dot: lane owns codes 8*lane..+7; d-ascending fmaf (np chain)
            float d0 = 0.f, d1 = 0.f, d2 = 0.f, d3 = 0.f;
            float d4 = 0.f, d5 = 0.f, d6 = 0.f, d7 = 0.f;
            const float* Ep = E + 8 * lane;
            #pragma unroll 4
            for (int d = 0; d < 64; ++d) {
                float xv = X[((size_t)(b * 64 + d)) * L_ + l0 + wave * 16 + tk];
                float4 e0 = *reinterpret_cast<const float4*>(Ep + d * K_);
                float4 e1 = *reinterpret_cast<const float4*>(Ep + d * K_ + 4);
                d0 = fmaf(xv, e0.x, d0); d1 = fmaf(xv, e0.y, d1);
                d2 = fmaf(xv, e0.z, d2); d3 = fmaf(xv, e0.w, d3);
                d4 = fmaf(xv, e1.x, d4); d5 = fmaf(xv, e1.y, d5);
                d6 = fmaf(xv, e1.z, d6); d7 = fmaf(xv, e1.w, d7);
            }
            float4 qa = *reinterpret_cast<const float4*>(&esq_s[8 * lane]);
            float4 qb = *reinterpret_cast<const float4*>(&esq_s[8 * lane + 4]);
            float sc[8];
            sc[0] = (xs_e - 2.0f * d0) + qa.x; sc[1] = (xs_e - 2.0f * d1) + qa.y;
            sc[2] = (xs_e - 2.0f * d2) + qa.z; sc[3] = (xs_e - 2.0f * d3) + qa.w;
            sc[4] = (xs_e - 2.0f * d4) + qb.x; sc[5] = (xs_e - 2.0f * d5) + qb.y;
            sc[6] = (xs_e - 2.0f * d6) + qb.z; sc[7] = (xs_e - 2.0f * d7) + qb.w;
            unsigned long long pk = ~0ULL;
            #pragma unroll
            for (int j = 0; j < 8; ++j) {        // ascending code: first-min kept
                unsigned long long p =
                    ((unsigned long long)f32_sortable(sc[j]) << 32) |
                    (unsigned)(8 * lane + j);
                if (p < pk) pk = p;
            }
            #pragma unroll
            for (int off = 1; off < 64; off <<= 1) {
                unsigned long long o = __shfl_xor(pk, off, 64);
                if (o < pk) pk = o;
            }
            int k_ex = (int)(unsigned)(pk & 0xFFFFFFFFULL);
            if (lo4 == tk) k1 = k_ex;            // update all 4 hi4 copies
        }

        // ---- publish results; one barrier; block-wide float4 epilogue -----
        if (lane < 16) bestk_s[wave * 16 + lo4] = k1;
        __syncthreads();                                         // B-epi
        {
            int d  = tid >> 3;                   // 0..63
            int q8 = tid & 7;
            #pragma unroll
            for (int it = 0; it < 4; ++it) {
                int quad = q8 + it * 8;          // 0..31
                int i4 = quad * 4;
                int k0 = bestk_s[i4],     kk1 = bestk_s[i4 + 1];
                int k2 = bestk_s[i4 + 2], k3  = bestk_s[i4 + 3];
                float4 v;
                v.x = E[d * K_ + k0];  v.y = E[d * K_ + kk1];
                v.z = E[d * K_ + k2];  v.w = E[d * K_ + k3];
                *reinterpret_cast<float4*>(out_emb + ((size_t)(b * 64 + d)) * L_ + l0 + i4) = v;
            }
        }
        if (tid < TILE_TOK)
            out_idx[(size_t)b * L_ + l0 + tid] = (float)bestk_s[tid];
    }
}

extern "C" void kernel_launch(void* const* d_in, const int* in_sizes, int n_in,
                              void* d_out, int out_size, void* d_ws, size_t ws_size,
                              hipStream_t stream) {
    const float* X = (const float*)d_in[0];   // (B, D, L) fp32
    const float* E = (const float*)d_in[1];   // (D, K) fp32
    float* out     = (float*)d_out;
    float* out_emb = out;
    float* out_idx = out + (size_t)B_ * D_ * L_;
    vq_mfma_kernel<<<NBLOCKS, 512, 0, stream>>>(X, E, out_emb, out_idx);
}

// Round 18
// 64.785 us; speedup vs baseline: 1.2665x; 1.2665x over previous
//
#include <hip/hip_runtime.h>
#include <float.h>

#define B_ 16
#define D_ 64
#define L_ 8192
#define K_ 512
#define NBLOCKS 256
#define TILE_TOK 128
#define TILES_PER_BLOCK 4     // 1024 tiles / 256 blocks, 1 block/CU
#define EPS 0.0625f           // approx-score err (fp16 dot + reassoc) << EPS/2

// r18 = r14 (best, 65 us) minus the redundant B1 barrier. Hazard audit:
// post-B3 epilogue reads only bestk_s/E/globals (never xT/xAh), and
// bestk_s(t+1) writes are fenced from epilogue(t) reads by B2(t+1).
// 2 barriers/tile. r15-r17 lesson: the r13/14 structure (LDS-staged X,
// LDS exact pass, block float4 epilogue) beats all decoupled variants.

typedef __attribute__((ext_vector_type(8))) _Float16 half8;
typedef __attribute__((ext_vector_type(4))) float    f32x4;

__device__ __forceinline__ unsigned f32_sortable(float x) {
    unsigned u = __float_as_uint(x);
    return u ^ (((int)u >> 31) | 0x80000000u);   // ascending uint == ascending float
}

__global__ __launch_bounds__(512, 1)
void vq_mfma_kernel(const float* __restrict__ X, const float* __restrict__ E,
                    float* __restrict__ out_emb, float* __restrict__ out_idx)
{
    __shared__ __align__(16) short eF[32768];    // E fp16 A-frags: [blk][kh][fl] x8, 64 KB
    __shared__ __align__(16) short xAh[8192];    // X fp16 B-frags: [tb][kh][fl] x8, 16 KB
    __shared__ float xT[64][132];                // fp32 x, [d][token], 33.8 KB
    __shared__ float esq_s[K_];
    __shared__ int   bestk_s[TILE_TOK];

    const int tid  = threadIdx.x;
    const int lane = tid & 63;
    const int wave = tid >> 6;        // 0..7
    const int lo4  = lane & 15;
    const int hi4  = lane >> 4;

    // ---- esq: np sequential axis-0 (round square, ordered adds) — r9 verbatim
    {
        float s = 0.f;
        #pragma unroll
        for (int c = 0; c < 4; ++c) {
            float v[16];
            #pragma unroll
            for (int m = 0; m < 16; ++m) v[m] = E[(c * 16 + m) * K_ + tid];
            #pragma unroll
            for (int m = 0; m < 16; ++m) {
                float sq = v[m] * v[m];
                asm volatile("" : "+v"(sq));     // np rounds the square first
                s = s + sq;
            }
        }
        esq_s[tid] = s;
    }

    // ---- E fp16 A-frags into LDS (once; reused all tiles) ----
    // unit (blk,kh), frag-lane fl holds E[d = kh*32+(fl>>4)*8+j][code = blk*16+(fl&15)]
    {
        int fl = tid & 63, pr = tid >> 6;        // pr 0..7
        #pragma unroll
        for (int it = 0; it < 8; ++it) {
            int idx = it * 8 + pr;               // 0..63 = (blk, kh)
            int blk = idx >> 1, kh = idx & 1;
            half8 h;
            #pragma unroll
            for (int j = 0; j < 8; ++j)
                h[j] = (_Float16)E[(kh * 32 + (fl >> 4) * 8 + j) * K_ + blk * 16 + (fl & 15)];
            ((half8*)eF)[(blk * 2 + kh) * 64 + fl] = h;
        }
    }

    // ---- prefetch: tile 0's X into registers ----
    float pf[2][8];
    {
        int tile = blockIdx.x * TILES_PER_BLOCK;
        int b  = tile >> 6;
        int l0 = (tile & 63) << 7;
        const float* xb = X + ((size_t)(b * 64 + wave * 8)) * L_ + l0 + lane;
        #pragma unroll
        for (int hh = 0; hh < 2; ++hh)
            #pragma unroll
            for (int r = 0; r < 8; ++r)
                pf[hh][r] = xb[(size_t)r * L_ + hh * 64];
    }

    for (int t = 0; t < TILES_PER_BLOCK; ++t) {
        int tile = blockIdx.x * TILES_PER_BLOCK + t;
        int b  = tile >> 6;                      // tile / 64
        int l0 = (tile & 63) << 7;               // (tile % 64) * 128

        // (B1 deleted: epilogue(t-1) never reads xT/xAh; B3 fenced exact(t-1))

        // ---- STAGE_WRITE from prefetch regs (write-late) ----
        #pragma unroll
        for (int hh = 0; hh < 2; ++hh) {
            int tok = hh * 64 + lane;
            #pragma unroll
            for (int r = 0; r < 8; ++r) xT[wave * 8 + r][tok] = pf[hh][r];
            half8 h8;
            #pragma unroll
            for (int r = 0; r < 8; ++r) h8[r] = (_Float16)pf[hh][r];  // d=wave*8+r
            int tb = tok >> 4, kh = wave >> 2;
            int fl = (wave & 3) * 16 + (tok & 15);
            ((half8*)xAh)[(tb * 2 + kh) * 64 + fl] = h8;
        }

        // ---- issue next tile's loads NOW (latency hides under compute) ----
        if (t < TILES_PER_BLOCK - 1) {
            int nt = tile + 1;
            int nb  = nt >> 6;
            int nl0 = (nt & 63) << 7;
            const float* xb = X + ((size_t)(nb * 64 + wave * 8)) * L_ + nl0 + lane;
            #pragma unroll
            for (int hh = 0; hh < 2; ++hh)
                #pragma unroll
                for (int r = 0; r < 8; ++r)
                    pf[hh][r] = xb[(size_t)r * L_ + hh * 64];
        }
        __syncthreads();                                         // B2

        // ---- xsq: wave-local np pairwise-8; lane's token = wave*16 + (lane&15)
        float xs;
        {
            int token = wave * 16 + lo4;
            int ja = 2 * hi4, jb = ja + 1;
            float ra = 0.f, rb = 0.f;
            #pragma unroll
            for (int m = 0; m < 8; ++m) {
                float va = xT[m * 8 + ja][token];
                float vb = xT[m * 8 + jb][token];
                float sa = va * va, sb = vb * vb;
                asm volatile("" : "+v"(sa));     // np rounds squares first
                asm volatile("" : "+v"(sb));
                ra = ra + sa;                    // m ascending: np r8[j] order
                rb = rb + sb;
            }
            float s = ra + rb;                   // (r[2h] + r[2h+1])
            s = s + __shfl_xor(s, 16, 64);       // h=0: (r0+r1)+(r2+r3)
            s = s + __shfl_xor(s, 32, 64);       // h=0: full np pairwise tree
            xs = __shfl(s, lo4, 64);             // broadcast h=0 lane's value
        }

        // ---- token B-frags resident (8 regs) ----
        half8 bh0 = ((const half8*)xAh)[(wave * 2 + 0) * 64 + lane];
        half8 bh1 = ((const half8*)xAh)[(wave * 2 + 1) * 64 + lane];

        // ---- main: 32 code-blocks; shifted score (es - 2*dot); reg fold ----
        float m1 = FLT_MAX, m2 = FLT_MAX;
        int   k1 = 0x7FFFFFFF;
        #pragma unroll 8
        for (int blk = 0; blk < 32; ++blk) {
            half8 ah0 = ((const half8*)eF)[(blk * 2 + 0) * 64 + lane];
            half8 ah1 = ((const half8*)eF)[(blk * 2 + 1) * 64 + lane];
            f32x4 c = {0.f, 0.f, 0.f, 0.f};
            c = __builtin_amdgcn_mfma_f32_16x16x32_f16(ah0, bh0, c, 0, 0, 0);
            c = __builtin_amdgcn_mfma_f32_16x16x32_f16(ah1, bh1, c, 0, 0, 0);
            float4 es4 = *reinterpret_cast<const float4*>(&esq_s[blk * 16 + hi4 * 4]);
            float es[4] = {es4.x, es4.y, es4.z, es4.w};
            #pragma unroll
            for (int r = 0; r < 4; ++r) {
                float sc = fmaf(-2.0f, c[r], es[r]);   // xs const/token: gap invariant
                int   cd = blk * 16 + hi4 * 4 + r;     // ascending within lane
                if (sc < m1)      { m2 = m1; m1 = sc; k1 = cd; }
                else              { m2 = fminf(m2, sc); }
            }
        }

        // ---- merge 4 hi4-copies per token (xor 16, 32) — validated logic ---
        #pragma unroll
        for (int off = 16; off < 64; off <<= 1) {
            float ov = __shfl_xor(m1, off, 64);
            int   ok = __shfl_xor(k1, off, 64);
            float o2 = __shfl_xor(m2, off, 64);
            float n2 = fminf(fminf(m2, o2), fmaxf(m1, ov));
            if (ov < m1 || (ov == m1 && ok < k1)) { m1 = ov; k1 = ok; }
            m2 = n2;
        }

        // ---- flag near-ties; wave-local exact pass (np-bitexact, xT LDS) --
        unsigned long long bal = __ballot((lane < 16) && (m2 <= m1 + EPS));
        while (bal) {
            int tk = (int)__builtin_ctzll(bal);
            bal &= bal - 1;
            int token = wave * 16 + tk;
            float xs_e = __shfl(xs, tk, 64);
            float d0 = 0.f, d1 = 0.f, d2 = 0.f, d3 = 0.f;
            float d4 = 0.f, d5 = 0.f, d6 = 0.f, d7 = 0.f;
            const float* Ep = E + 8 * lane;
            #pragma unroll 4
            for (int d = 0; d < 64; ++d) {
                float xv = xT[d][token];         // wave-uniform broadcast
                float4 e0 = *reinterpret_cast<const float4*>(Ep + d * K_);
                float4 e1 = *reinterpret_cast<const float4*>(Ep + d * K_ + 4);
                d0 = fmaf(xv, e0.x, d0); d1 = fmaf(xv, e0.y, d1);
                d2 = fmaf(xv, e0.z, d2); d3 = fmaf(xv, e0.w, d3);
                d4 = fmaf(xv, e1.x, d4); d5 = fmaf(xv, e1.y, d5);
                d6 = fmaf(xv, e1.z, d6); d7 = fmaf(xv, e1.w, d7);
            }
            float4 qa = *reinterpret_cast<const float4*>(&esq_s[8 * lane]);
            float4 qb = *reinterpret_cast<const float4*>(&esq_s[8 * lane + 4]);
            float sc[8];
            sc[0] = (xs_e - 2.0f * d0) + qa.x; sc[1] = (xs_e - 2.0f * d1) + qa.y;
            sc[2] = (xs_e - 2.0f * d2) + qa.z; sc[3] = (xs_e - 2.0f * d3) + qa.w;
            sc[4] = (xs_e - 2.0f * d4) + qb.x; sc[5] = (xs_e - 2.0f * d5) + qb.y;
            sc[6] = (xs_e - 2.0f * d6) + qb.z; sc[7] = (xs_e - 2.0f * d7) + qb.w;
            unsigned long long pk = ~0ULL;
            #pragma unroll
            for (int j = 0; j < 8; ++j) {        // ascending code: first-min kept
                unsigned long long p =
                    ((unsigned long long)f32_sortable(sc[j]) << 32) |
                    (unsigned)(8 * lane + j);
                if (p < pk) pk = p;
            }
            #pragma unroll
            for (int off = 1; off < 64; off <<= 1) {
                unsigned long long o = __shfl_xor(pk, off, 64);
                if (o < pk) pk = o;
            }
            if (lane == 0)
                bestk_s[token] = (int)(unsigned)(pk & 0xFFFFFFFFULL);
        }
        if (lane < 16) {
            // non-flagged tokens: publish approx winner (np argmin)
            if (!((m2 <= m1 + EPS))) bestk_s[wave * 16 + lo4] = k1;
        }
        __syncthreads();                                         // B3

        // ---- epilogue: gather exact fp32 rows, float4 stores, 128 tokens --
        {
            int d  = tid >> 3;                   // 0..63
            int q8 = tid & 7;
            #pragma unroll
            for (int it = 0; it < 4; ++it) {
                int quad = q8 + it * 8;          // 0..31
                int i4 = quad * 4;
                int k0 = bestk_s[i4],     kk1 = bestk_s[i4 + 1];
                int k2 = bestk_s[i4 + 2], k3  = bestk_s[i4 + 3];
                float4 v;
                v.x = E[d * K_ + k0];  v.y = E[d * K_ + kk1];
                v.z = E[d * K_ + k2];  v.w = E[d * K_ + k3];
                *reinterpret_cast<float4*>(out_emb + ((size_t)(b * 64 + d)) * L_ + l0 + i4) = v;
            }
        }
        if (tid < TILE_TOK)
            out_idx[(size_t)b * L_ + l0 + tid] = (float)bestk_s[tid];
    }
}

extern "C" void kernel_launch(void* const* d_in, const int* in_sizes, int n_in,
                              void* d_out, int out_size, void* d_ws, size_t ws_size,
                              hipStream_t stream) {
    const float* X = (const float*)d_in[0];   // (B, D, L) fp32
    const float* E = (const float*)d_in[1];   // (D, K) fp32
    float* out     = (float*)d_out;
    float* out_emb = out;
    float* out_idx = out + (size_t)B_ * D_ * L_;
    vq_mfma_kernel<<<NBLOCKS, 512, 0, stream>>>(X, E, out_emb, out_idx);
}